// Round 7
// baseline (51.660 us; speedup 1.0000x reference)
//
#include <hip/hip_runtime.h>

#define WINDOW 48
#define RES 50
#define PRED 96
#define SEG 100
#define BATCH 2048
#define KTRUNC 12

// LDS swizzle: row j lives at float offset 52*j + 4*(j/10)  (16B-aligned rows,
// tile-to-tile bank offset +12 -> all row groups spread over banks, <=2-way)

// ws layout (floats):
//   M  [50][48]   @ 0      (2400)
//   Dk [16][50]   @ 2400   (800)
//   Wt [50][96]   @ 3200   (4800)
//   DP [10][50]   @ 8000   (500)    DP[wt][c] = d_c^(10*(9-wt))
//   L  [2048][50] @ 8500   (102400)

__global__ __launch_bounds__(128) void k0_setup(const float* __restrict__ W_lin,
                                                const float* __restrict__ W_in,
                                                const float* __restrict__ d,
                                                const float* __restrict__ W_out,
                                                float* __restrict__ ws) {
    float* M  = ws;
    float* Dk = ws + 2400;
    float* Wt = ws + 3200;
    float* DP = ws + 8000;
    int f = blockIdx.x * 128 + threadIdx.x;
    if (f < 2400) {
        int r = f / WINDOW, w = f % WINDOW;
        float acc = 0.f;
        for (int v = 0; v < WINDOW; ++v)
            acc = fmaf(W_in[r * WINDOW + v], W_lin[v * WINDOW + w], acc);
        M[f] = acc;
    } else if (f < 7200) {
        int e = f - 2400;               // Wt[r][o] = W_out[o][r]
        int r = e / PRED, o = e % PRED;
        Wt[e] = W_out[o * RES + r];
    } else if (f < 7700) {
        int e = f - 7200;               // DP[wt][c] = (d_c^10)^(9-wt)
        int wt = e / RES, c = e % RES;
        float dv = d[c];
        float d2 = dv * dv, d4 = d2 * d2, d5 = d4 * dv, d10 = d5 * d5;
        float pw = 1.f;
        for (int k = wt; k < 9; ++k) pw *= d10;
        DP[e] = pw;
    } else if (f < 7750) {
        int c = f - 7700;
        float dv = d[c];
        float d2 = dv * dv, d4 = d2 * d2, d8 = d4 * d4;
        float d16 = d8 * d8, d32 = d16 * d16, d64 = d32 * d32;
        float D = d64 * d32 * d4;       // d^100
        float p = 1.f;
        for (int k = 0; k < 16; ++k) { Dk[k * RES + c] = p; p *= D; }
    }
}

// One block = one wave = one batch. Lane t<50: wt = t/5 (10 windows 10wt..10wt+9),
// ct = t%5 (10 channels 10ct..10ct+9). 100 accumulators/lane.
// Per kc (12 chunks of 4): 10 x-b128 + 10 m-b128 -> 400 FMAs.
// Then per-channel 10-term Horner * DP weight -> Ps, 10-way reduce -> L.
__global__ __launch_bounds__(64, 2) void k1_local(const float* __restrict__ x,
                                                  const float* __restrict__ ws,
                                                  const float* __restrict__ d,
                                                  float* __restrict__ L) {
    __shared__ float Xs[5240];   // 100 swizzled rows of x
    __shared__ float Ms[2620];   // 50 swizzled rows of M
    const float* Mg = ws;
    const float* DP = ws + 8000;

    int b = blockIdx.x;
    int t = threadIdx.x;

    // --- stage x (coalesced float4, swizzled rows) ---
    const float4* xr4 = (const float4*)(x + (size_t)b * (SEG * WINDOW));
    for (int e = t; e < 1200; e += 64) {
        int j = e / 12, q = e % 12;
        *(float4*)(Xs + 52 * j + 4 * (j / 10) + 4 * q) = xr4[e];
    }
    // --- stage M ---
    const float4* mr4 = (const float4*)Mg;
    for (int e = t; e < 600; e += 64) {
        int r = e / 12, q = e % 12;
        *(float4*)(Ms + 52 * r + 4 * (r / 10) + 4 * q) = mr4[e];
    }

    int wt = t / 5;          // 0..9 for t<50
    int ct = t % 5;          // 0..4
    int c0 = 10 * ct;
    int xbase = 524 * wt;    // row 10wt+i at xbase + 52*i
    int mbase = 524 * ct;    // row 10ct+cc at mbase + 52*cc

    float dreg[10], dpreg[10];
    if (t < 50) {            // prefetch weights (hide under staging latency)
#pragma unroll
        for (int cc = 0; cc < 10; ++cc) dreg[cc] = d[c0 + cc];
#pragma unroll
        for (int cc = 0; cc < 10; ++cc) dpreg[cc] = DP[wt * RES + c0 + cc];
    }
    __syncthreads();

    float acc[10][10];
    if (t < 50) {
#pragma unroll
        for (int i = 0; i < 10; ++i)
#pragma unroll
            for (int cc = 0; cc < 10; ++cc) acc[i][cc] = 0.f;

        for (int kc = 0; kc < 12; ++kc) {
            int xo = 4 * kc;
            float4 xv[10];
#pragma unroll
            for (int i = 0; i < 10; ++i)
                xv[i] = *(const float4*)(Xs + xbase + 52 * i + xo);
#pragma unroll
            for (int cc = 0; cc < 10; ++cc) {
                float4 mv = *(const float4*)(Ms + mbase + 52 * cc + xo);
#pragma unroll
                for (int i = 0; i < 10; ++i) {
                    float a = acc[i][cc];
                    a = fmaf(xv[i].x, mv.x, a);
                    a = fmaf(xv[i].y, mv.y, a);
                    a = fmaf(xv[i].z, mv.z, a);
                    a = fmaf(xv[i].w, mv.w, a);
                    acc[i][cc] = a;
                }
            }
        }
    }
    __syncthreads();          // Xs reads done -> alias as partials Ps[10][51]
    float* Ps = Xs;
    if (t < 50) {
#pragma unroll
        for (int cc = 0; cc < 10; ++cc) {
            float dv = dreg[cc];
            float h = acc[0][cc];
#pragma unroll
            for (int i = 1; i < 10; ++i) h = fmaf(h, dv, acc[i][cc]);
            Ps[wt * 51 + c0 + cc] = h * dpreg[cc];   // weight d^(10*(9-wt))
        }
    }
    __syncthreads();
    if (t < RES) {
        float s = 0.f;
#pragma unroll
        for (int q = 0; q < 10; ++q) s += Ps[q * 51 + t];
        L[b * RES + t] = s;
    }
}

// One block per batch: s[r] = sum_k Dk[k][r]*L[b-k][r]; out[b][o] = sum_r s[r]*Wt[r][o]
__global__ __launch_bounds__(128) void k2_out(const float* __restrict__ L,
                                              const float* __restrict__ Dk,
                                              const float* __restrict__ Wt,
                                              float* __restrict__ out) {
    __shared__ float s_s[52];
    int b = blockIdx.x;
    int t = threadIdx.x;
    if (t < RES) {
        float acc = 0.f;
#pragma unroll
        for (int k = 0; k < KTRUNC; ++k) {
            int bb = b - k;
            if (bb >= 0) acc = fmaf(Dk[k * RES + t], L[bb * RES + t], acc);
        }
        s_s[t] = acc;
    }
    __syncthreads();
    if (t < PRED) {
        float acc = 0.f;
#pragma unroll 10
        for (int r = 0; r < RES; ++r)
            acc = fmaf(s_s[r], Wt[r * PRED + t], acc);
        out[b * PRED + t] = acc;
    }
}

extern "C" void kernel_launch(void* const* d_in, const int* in_sizes, int n_in,
                              void* d_out, int out_size, void* d_ws, size_t ws_size,
                              hipStream_t stream) {
    const float* x     = (const float*)d_in[0];
    const float* W_lin = (const float*)d_in[1];
    const float* W_in  = (const float*)d_in[2];
    const float* d     = (const float*)d_in[3];
    const float* W_out = (const float*)d_in[4];
    float* out = (float*)d_out;
    float* ws  = (float*)d_ws;

    float* Dk = ws + 2400;
    float* Wt = ws + 3200;
    float* L  = ws + 8500;

    k0_setup<<<61, 128, 0, stream>>>(W_lin, W_in, d, W_out, ws);
    k1_local<<<BATCH, 64, 0, stream>>>(x, ws, d, L);
    k2_out<<<BATCH, 128, 0, stream>>>(L, Dk, Wt, out);
}